// Round 6
// baseline (193.328 us; speedup 1.0000x reference)
//
#include <hip/hip_runtime.h>
#include <stdint.h>

#define B_SZ 8192
#define D_SZ 1024
#define H_SZ 4096
#define O_SZ 1000

#define MARGIN 0.0625f

typedef float f32x4 __attribute__((ext_vector_type(4)));
typedef float f32x16 __attribute__((ext_vector_type(16)));
typedef __bf16 bf16x8 __attribute__((ext_vector_type(8)));

// ---------------- fp32 -> bf16 (round-to-nearest-even) ----------------
static __device__ __forceinline__ uint16_t f2bf(float f) {
  uint32_t u = __float_as_uint(f);
  uint32_t r = (u + 0x7fffu + ((u >> 16) & 1u)) >> 16;
  return (uint16_t)r;
}

__global__ __launch_bounds__(256) void convert_bf16(const float* __restrict__ src,
                                                    ushort4* __restrict__ dst, int n4) {
  int i = blockIdx.x * blockDim.x + threadIdx.x;
  if (i < n4) {
    f32x4 v = reinterpret_cast<const f32x4*>(src)[i];
    ushort4 o;
    o.x = f2bf(v[0]); o.y = f2bf(v[1]); o.z = f2bf(v[2]); o.w = f2bf(v[3]);
    dst[i] = o;
  }
}

// ---------------- w2 in f64 (exact score needs it) ----------------
__global__ __launch_bounds__(64) void w2_kernel(const float* __restrict__ w,
                                                double* __restrict__ w2d) {
  const int h = blockIdx.x;
  const int l = threadIdx.x;
  const f32x4* wr = reinterpret_cast<const f32x4*>(w + (size_t)h * D_SZ);
  double s = 0.0;
#pragma unroll
  for (int j = 0; j < 4; ++j) {
    f32x4 v = wr[j * 64 + l];
    s += (double)v[0] * v[0] + (double)v[1] * v[1] + (double)v[2] * v[2] + (double)v[3] * v[3];
  }
#pragma unroll
  for (int m = 32; m; m >>= 1) s += __shfl_xor(s, m);
  if (l == 0) w2d[h] = s;
}

// ---------------- phase 1: 128x128 GEMM with 32x32x16 MFMA ----------------
// 4 waves (2x2), per-wave C = 64x64 = 2x2 frags of 32x32. BK=64 (4 k-slices of 16).
// 32x32x16 halves LDS bytes/FLOP vs 16x16x32 (16 vs 8 FLOP/B) and is the fastest
// measured MFMA shape (m119: 2495 TF). LDS = 2 parities x (A 16KB + B 16KB) = 64KB
// -> 2 independent blocks/CU: inter-block overlap hides barrier/vmcnt stalls (m114).
// Staging: global_load_lds width-16, linear dest; counted s_waitcnt vmcnt(8) + raw
// s_barrier (no compiler vmcnt(0) drain); prefetch distance = 1 full K-tile.
// Fragment-read bank fix (derived): fixed (mi,ks) touches only quads {ks*2, ks*2+1}
// (32 lanes each) in a linear [128][64] tile -> 4x floor. XOR chunk bits 1..2 with
// row&3: byte ^= (row&3)<<5 -> 8 quads x 8 lanes = b128 floor. Applied via
// pre-swizzled GLOBAL SOURCE (linear glds dest, rule #21) + XOR on ds_read address.
__global__ __launch_bounds__(256, 2) void kohonen_gemm(const uint16_t* __restrict__ xb,
                                                       const uint16_t* __restrict__ wb,
                                                       float* __restrict__ tmax64,
                                                       unsigned long long* __restrict__ tmask64) {
  __shared__ __align__(16) char As[32768];  // [2 parity][128][64] bf16, chunk-swizzled
  __shared__ __align__(16) char Bs[32768];
  const int tid = threadIdx.x;
  const int lane = tid & 63, wv = tid >> 6;
  const int wm = wv >> 1, wn = wv & 1;
  const int l31 = lane & 31, hi = lane >> 5;

  // XCD-bijective swizzle: 2048 blocks = 8 XCDs x 256
  const int bid = blockIdx.x;
  const int wg = (bid & 7) * 256 + (bid >> 3);
  const int bm = wg >> 5, bn = wg & 31;

  const uint16_t* xrow = xb + (size_t)(bm * 128) * D_SZ;
  const uint16_t* wrow = wb + (size_t)(bn * 128) * D_SZ;

  f32x16 acc00 = {}, acc01 = {}, acc10 = {}, acc11 = {};

  // staging: 4 calls per matrix per wave; call i -> LDS rows [ (wv*4+i)*8, +8 ).
  // dest linear; source 16B-part pre-swizzled: part = (lane&7) ^ (((lane>>3)&3)<<1)
  const int st_row = (lane >> 3);                                  // 0..7 within call
  const int st_part = (lane & 7) ^ (((lane >> 3) & 3) << 1);       // inverse swizzle
  auto stage = [&](int sp, int kt) {
#pragma unroll
    for (int i = 0; i < 4; ++i) {
      const int blk = wv * 4 + i;           // 0..15, 8 rows each
      const int row = blk * 8 + st_row;
      const uint16_t* sa = xrow + (size_t)row * D_SZ + kt * 64 + st_part * 8;
      __builtin_amdgcn_global_load_lds(
          (const __attribute__((address_space(1))) uint32_t*)sa,
          (__attribute__((address_space(3))) uint32_t*)(As + sp * 16384 + blk * 1024),
          16, 0, 0);
      const uint16_t* sb = wrow + (size_t)row * D_SZ + kt * 64 + st_part * 8;
      __builtin_amdgcn_global_load_lds(
          (const __attribute__((address_space(1))) uint32_t*)sb,
          (__attribute__((address_space(3))) uint32_t*)(Bs + sp * 16384 + blk * 1024),
          16, 0, 0);
    }
  };

  // fragment read: row's k-slice (ks*2+hi) lives at chunk (row*8 + ((ks*2+hi)^((row&3)<<1)))
  auto ldfrag = [&](const char* base, int row, int ks) -> bf16x8 {
    const int byte = (row * 128 + ks * 32 + hi * 16) ^ ((row & 3) << 5);
    return *reinterpret_cast<const bf16x8*>(base + byte);
  };

  stage(0, 0);  // prologue: tile 0 -> parity 0

  for (int t = 0; t < 16; ++t) {
    const int rp = t & 1, sp = rp ^ 1;
    if (t < 15) {
      stage(sp, t + 1);
      asm volatile("s_waitcnt vmcnt(8)" ::: "memory");  // tile t done; t+1's 8 in flight
    } else {
      asm volatile("s_waitcnt vmcnt(0)" ::: "memory");
    }
    __builtin_amdgcn_s_barrier();
    const char* Ab = As + rp * 16384;
    const char* Bb = Bs + rp * 16384;
#pragma unroll
    for (int ks = 0; ks < 4; ++ks) {
      bf16x8 a0 = ldfrag(Ab, wm * 64 + l31, ks);
      bf16x8 a1 = ldfrag(Ab, wm * 64 + 32 + l31, ks);
      bf16x8 b0 = ldfrag(Bb, wn * 64 + l31, ks);
      bf16x8 b1 = ldfrag(Bb, wn * 64 + 32 + l31, ks);
      acc00 = __builtin_amdgcn_mfma_f32_32x32x16_bf16(a0, b0, acc00, 0, 0, 0);
      acc01 = __builtin_amdgcn_mfma_f32_32x32x16_bf16(a0, b1, acc01, 0, 0, 0);
      acc10 = __builtin_amdgcn_mfma_f32_32x32x16_bf16(a1, b0, acc10, 0, 0, 0);
      acc11 = __builtin_amdgcn_mfma_f32_32x32x16_bf16(a1, b1, acc11, 0, 0, 0);
    }
    asm volatile("s_waitcnt lgkmcnt(0)" ::: "memory");  // reads of rp done before overwrite
    __builtin_amdgcn_s_barrier();
  }

  // epilogue: per row, (max, within-margin bitmask) over this wave's 64 h.
  // 32x32 C/D layout (m74/m101-verified): col = lane&31, row = (r&3) + 8*(r>>2) + 4*hi.
  const int tile = bn * 2 + wn;
#pragma unroll
  for (int mi = 0; mi < 2; ++mi) {
    const f32x16 c0 = mi ? acc10 : acc00;
    const f32x16 c1 = mi ? acc11 : acc01;
#pragma unroll
    for (int r = 0; r < 16; ++r) {
      float v = fmaxf(c0[r], c1[r]);
#pragma unroll
      for (int s = 1; s < 32; s <<= 1) v = fmaxf(v, __shfl_xor(v, s));  // within 32-half
      const float thr = v - MARGIN;
      unsigned long long mk = (c0[r] >= thr ? (1ull << l31) : 0ull) |
                              (c1[r] >= thr ? (1ull << (32 + l31)) : 0ull);
#pragma unroll
      for (int s = 1; s < 32; s <<= 1) mk |= __shfl_xor(mk, s);
      if (l31 == 0) {
        const int row = bm * 128 + wm * 64 + mi * 32 + (r & 3) + 8 * (r >> 2) + 4 * hi;
        tmax64[(size_t)row * 64 + tile] = v;
        tmask64[(size_t)row * 64 + tile] = mk;
      }
    }
  }
}

// ---------------- phase 2: exact f64 rescore of candidate h's (one wave per row) ----------------
__global__ __launch_bounds__(64) void rescore2(const float* __restrict__ x,
                                               const float* __restrict__ w,
                                               const double* __restrict__ w2d,
                                               const float* __restrict__ tmax64,
                                               const unsigned long long* __restrict__ tmask64,
                                               int* __restrict__ winners,
                                               float* __restrict__ winners_f) {
  const int row = blockIdx.x;
  const int l = threadIdx.x;

  f32x4 xr[4];
  const f32x4* xp = reinterpret_cast<const f32x4*>(x + (size_t)row * D_SZ);
#pragma unroll
  for (int j = 0; j < 4; ++j) xr[j] = xp[j * 64 + l];

  const float pmax = tmax64[(size_t)row * 64 + l];
  const unsigned long long pmask = tmask64[(size_t)row * 64 + l];
  float M = pmax;
#pragma unroll
  for (int m = 1; m < 64; m <<= 1) M = fmaxf(M, __shfl_xor(M, m));
  const float thr = M - MARGIN;

  double bestS = -1e300;
  int bestI = 0x7fffffff;

  unsigned long long bits = __ballot(pmax >= thr && pmask != 0ull);
  while (bits) {
    const int src = __ffsll(bits) - 1;
    unsigned long long tmask = __shfl(pmask, src);
    const int tile = src;
    while (tmask) {
      const int b = __ffsll(tmask) - 1;
      const int h = tile * 64 + b;
      const f32x4* wp = reinterpret_cast<const f32x4*>(w + (size_t)h * D_SZ);
      double dot = 0.0;
#pragma unroll
      for (int j = 0; j < 4; ++j) {
        f32x4 wv = wp[j * 64 + l];
        dot += (double)xr[j][0] * wv[0] + (double)xr[j][1] * wv[1] +
               (double)xr[j][2] * wv[2] + (double)xr[j][3] * wv[3];
      }
#pragma unroll
      for (int m = 32; m; m >>= 1) dot += __shfl_xor(dot, m);
      const double sc = 2.0 * dot - w2d[h];  // maximize  <=>  minimize d2
      if (sc > bestS || (sc == bestS && h < bestI)) { bestS = sc; bestI = h; }
      tmask &= tmask - 1;
    }
    bits &= bits - 1;
  }

  if (l == 0) { winners[row] = bestI; winners_f[row] = (float)bestI; }
}

// ---------------- phase 3a: transpose grossberg [O][H] -> GT [H][O] ----------------
__global__ __launch_bounds__(256) void transpose_g(const float* __restrict__ g,
                                                   float* __restrict__ gt) {
  __shared__ float t[32][33];
  const int h0 = blockIdx.x * 32;
  const int o0 = blockIdx.y * 32;
  const int lx = threadIdx.x & 31, ly = threadIdx.x >> 5;
  for (int i = ly; i < 32; i += 8) {
    const int o = o0 + i;
    t[i][lx] = (o < O_SZ) ? g[(size_t)o * H_SZ + (h0 + lx)] : 0.f;
  }
  __syncthreads();
  for (int i = ly; i < 32; i += 8) {
    const int o = o0 + lx;
    if (o < O_SZ) gt[(size_t)(h0 + i) * O_SZ + o] = t[lx][i];
  }
}

// ---------------- phase 3b: row gather + scalar ----------------
__global__ __launch_bounds__(256) void gather_out(const float* __restrict__ gt,
                                                  const int* __restrict__ winners,
                                                  float* __restrict__ out) {
  const int row = blockIdx.x;
  const int wsel = winners[row];
  const f32x4* src = reinterpret_cast<const f32x4*>(gt + (size_t)wsel * O_SZ);
  f32x4* dst = reinterpret_cast<f32x4*>(out + (size_t)row * O_SZ);
  if (threadIdx.x < O_SZ / 4) dst[threadIdx.x] = src[threadIdx.x];
  if (row == 0 && threadIdx.x == 0)
    out[(size_t)B_SZ * O_SZ + B_SZ] = (float)B_SZ;  // scalar output: x.shape[0]
}

// ---------------- launch ----------------
extern "C" void kernel_launch(void* const* d_in, const int* in_sizes, int n_in,
                              void* d_out, int out_size, void* d_ws, size_t ws_size,
                              hipStream_t stream) {
  const float* x  = (const float*)d_in[0];
  const float* kw = (const float*)d_in[1];
  const float* gw = (const float*)d_in[2];
  float* out = (float*)d_out;
  char* ws = (char*)d_ws;

  // ws layout (bytes):
  //   xb      @ 0          : 8192*1024*2 = 16,777,216
  //   wb      @ 16,777,216 : 4096*1024*2 =  8,388,608
  //   tmax64  @ 25,165,824 : 8192*64*4   =  2,097,152
  //   tmask64 @ 27,262,976 : 8192*64*8   =  4,194,304
  //   winners @ 31,457,280 : 8192*4      =     32,768
  //   w2d     @ 31,490,048 : 4096*8      =     32,768
  //   GT aliases xb (16,384,000 <= 16,777,216; xb is dead after phase 1)
  uint16_t*           xb   = (uint16_t*)(ws);
  uint16_t*           wb   = (uint16_t*)(ws + 16777216);
  float*              tmx  = (float*)   (ws + 25165824);
  unsigned long long* tmk  = (unsigned long long*)(ws + 27262976);
  int*                wins = (int*)     (ws + 31457280);
  double*             w2d  = (double*)  (ws + 31490048);
  float*              gt   = (float*)   (ws);  // alias of xb, used after phase 2

  convert_bf16<<<(B_SZ * D_SZ / 4 + 255) / 256, 256, 0, stream>>>(x, (ushort4*)xb, B_SZ * D_SZ / 4);
  convert_bf16<<<(H_SZ * D_SZ / 4 + 255) / 256, 256, 0, stream>>>(kw, (ushort4*)wb, H_SZ * D_SZ / 4);
  w2_kernel<<<H_SZ, 64, 0, stream>>>(kw, w2d);

  kohonen_gemm<<<2048, 256, 0, stream>>>(xb, wb, tmx, tmk);

  rescore2<<<B_SZ, 64, 0, stream>>>(x, kw, w2d, tmx, tmk, wins, out + (size_t)B_SZ * O_SZ);

  dim3 g3(H_SZ / 32, (O_SZ + 31) / 32);
  transpose_g<<<g3, 256, 0, stream>>>(gw, gt);

  gather_out<<<B_SZ, 256, 0, stream>>>(gt, wins, out);
}

// Round 8
// 130.688 us; speedup vs baseline: 1.4793x; 1.4793x over previous
//
#include <hip/hip_runtime.h>
#include <stdint.h>

#define B_SZ 8192
#define D_SZ 1024
#define H_SZ 4096
#define O_SZ 1000

#define MARGIN 0.0625f

typedef float f32x4 __attribute__((ext_vector_type(4)));
typedef __bf16 bf16x8 __attribute__((ext_vector_type(8)));

// ---------------- fp32 -> bf16 (round-to-nearest-even) ----------------
static __device__ __forceinline__ uint16_t f2bf(float f) {
  uint32_t u = __float_as_uint(f);
  uint32_t r = (u + 0x7fffu + ((u >> 16) & 1u)) >> 16;
  return (uint16_t)r;
}

__global__ __launch_bounds__(256) void convert_bf16(const float* __restrict__ src,
                                                    ushort4* __restrict__ dst, int n4) {
  int i = blockIdx.x * blockDim.x + threadIdx.x;
  if (i < n4) {
    f32x4 v = reinterpret_cast<const f32x4*>(src)[i];
    ushort4 o;
    o.x = f2bf(v[0]); o.y = f2bf(v[1]); o.z = f2bf(v[2]); o.w = f2bf(v[3]);
    dst[i] = o;
  }
}

// ---------------- w2 in f64 (exact score needs it) ----------------
__global__ __launch_bounds__(64) void w2_kernel(const float* __restrict__ w,
                                                double* __restrict__ w2d) {
  const int h = blockIdx.x;
  const int l = threadIdx.x;
  const f32x4* wr = reinterpret_cast<const f32x4*>(w + (size_t)h * D_SZ);
  double s = 0.0;
#pragma unroll
  for (int j = 0; j < 4; ++j) {
    f32x4 v = wr[j * 64 + l];
    s += (double)v[0] * v[0] + (double)v[1] * v[1] + (double)v[2] * v[2] + (double)v[3] * v[3];
  }
#pragma unroll
  for (int m = 32; m; m >>= 1) s += __shfl_xor(s, m);
  if (l == 0) w2d[h] = s;
}

// ---------------- phase 1: 256x256 8-phase bf16 MFMA GEMM (24-read, R4 wait discipline) --
// 8 waves (2M x 4N), per-wave C = 128x64 (8 m-frags x 4 n-frags of 16x16), BK=64.
// Register-resident operands across the K-tile (24 ds_read_b128/K-tile/wave vs R4's 48):
//   ph0: read A(qm0) 8 + B(qn0) 4 ; stage A-slot0(t+1); vmcnt(4); bar; MFMA(0,0); bar
//   ph1: read B(qn1) 4            ; stage B-slot0(t+1); vmcnt(4); bar; MFMA(0,1); bar
//   ph2: read A(qm1) 8            ; stage B-slot1(t+1); vmcnt(4); bar; MFMA(1,1); bar
//   ph3: (no reads)               ; stage A-slot1(t+1); vmcnt(4); bar; MFMA(1,0); bar
// FIFO proof (P=prev-iter stages, S=this-iter): prologue vmcnt(4) retires P1..P4 before
// iter0-ph0 reads; ph0 vmcnt (10 issued -> 4 out) retires P5,P6 before ph1's B1 read;
// ph1 vmcnt retires P7,P8 before ph2's A1 read; ph3 vmcnt retires S1..S4 before next
// ph0's reads. vmcnt is AFTER the stage issue (R6's before-stage placement raced: ph0's
// wait saw only 4 outstanding and guaranteed nothing for B1/A1 — the absmax-3985 bug).
__global__ __launch_bounds__(512, 2) void kohonen_gemm256(const uint16_t* __restrict__ xb,
                                                          const uint16_t* __restrict__ wb,
                                                          float* __restrict__ tmax64,
                                                          unsigned long long* __restrict__ tmask64) {
  extern __shared__ char smem[];  // 131072 B: A slots @0, B slots @65536
  const int tid = threadIdx.x;
  const int lane = tid & 63, wid = tid >> 6;
  const int wm = wid >> 2, wn = wid & 3;
  const int r15 = lane & 15, g = lane >> 4;
  const int xorv = ((r15 >> 1) & 1) << 6;
  const int lr = lane >> 3, lp = lane & 7;  // staging: row-within-8, 16B part

  // XCD-bijective swizzle: 512 blocks = 8 XCDs x 64
  const int bid = blockIdx.x;
  const int wg = (bid & 7) * 64 + (bid >> 3);
  const int bm = wg >> 4, bn = wg & 15;

  const uint16_t* xrow = xb + (size_t)(bm * 256) * D_SZ;
  const uint16_t* wrow = wb + (size_t)(bn * 256) * D_SZ;

  f32x4 acc[8][4] = {};
  bf16x8 Af[4][2];      // current qm-half of A: [mi][ks]
  bf16x8 Bf[2][2][2];   // both qn-halves of B: [qn][ni][ks]

  auto stage_a = [&](int a, int sp, int kt) {
#pragma unroll
    for (int j = 0; j < 2; ++j) {
      const int sr = wid * 16 + j * 8 + lr;
      const int pp = lp ^ (((sr >> 1) & 1) << 2);
      const int mr = (sr < 64) ? (a * 64 + sr) : (128 + a * 64 + (sr - 64));
      const uint16_t* src = xrow + (size_t)mr * D_SZ + kt * 64 + pp * 8;
      __builtin_amdgcn_global_load_lds(
          (const __attribute__((address_space(1))) uint32_t*)src,
          (__attribute__((address_space(3))) uint32_t*)(smem + (sp * 2 + a) * 16384 +
                                                        (wid * 16 + j * 8) * 128),
          16, 0, 0);
    }
  };
  auto stage_b = [&](int b, int sp, int kt) {
#pragma unroll
    for (int j = 0; j < 2; ++j) {
      const int sr = wid * 16 + j * 8 + lr;
      const int pp = lp ^ (((sr >> 1) & 1) << 2);
      const int mr = (sr >> 5) * 64 + b * 32 + (sr & 31);
      const uint16_t* src = wrow + (size_t)mr * D_SZ + kt * 64 + pp * 8;
      __builtin_amdgcn_global_load_lds(
          (const __attribute__((address_space(1))) uint32_t*)src,
          (__attribute__((address_space(3))) uint32_t*)(smem + 65536 + (sp * 2 + b) * 16384 +
                                                        (wid * 16 + j * 8) * 128),
          16, 0, 0);
    }
  };

#define LDA(QM)                                                                  \
  {                                                                              \
    const char* Abq = smem + rp * 32768 + (QM)*16384;                            \
    _Pragma("unroll") for (int mi = 0; mi < 4; ++mi) {                           \
      const int sr = wm * 64 + mi * 16 + r15;                                    \
      _Pragma("unroll") for (int ks = 0; ks < 2; ++ks)                           \
          Af[mi][ks] = *reinterpret_cast<const bf16x8*>(                         \
              Abq + ((sr * 128 + ks * 64 + g * 16) ^ xorv));                     \
    }                                                                            \
  }
#define LDB(QN)                                                                  \
  {                                                                              \
    const char* Bbq = smem + 65536 + rp * 32768 + (QN)*16384;                    \
    _Pragma("unroll") for (int ni = 0; ni < 2; ++ni) {                           \
      const int sr = wn * 32 + ni * 16 + r15;                                    \
      _Pragma("unroll") for (int ks = 0; ks < 2; ++ks)                           \
          Bf[QN][ni][ks] = *reinterpret_cast<const bf16x8*>(                     \
              Bbq + ((sr * 128 + ks * 64 + g * 16) ^ xorv));                     \
    }                                                                            \
  }
#define MFMAQ(QM, QN)                                                            \
  __builtin_amdgcn_s_setprio(1);                                                 \
  _Pragma("unroll") for (int mi = 0; mi < 4; ++mi)                               \
      _Pragma("unroll") for (int ni = 0; ni < 2; ++ni)                           \
          _Pragma("unroll") for (int ks = 0; ks < 2; ++ks)                       \
              acc[(QM)*4 + mi][(QN)*2 + ni] = __builtin_amdgcn_mfma_f32_16x16x32_bf16( \
                  Af[mi][ks], Bf[QN][ni][ks], acc[(QM)*4 + mi][(QN)*2 + ni], 0, 0, 0); \
  __builtin_amdgcn_s_setprio(0);

  // prologue: tile 0 -> parity 0, order A0,B0,B1,A1; then retire A0,B0 before iter0 reads
  stage_a(0, 0, 0);
  stage_b(0, 0, 0);
  stage_b(1, 0, 0);
  stage_a(1, 0, 0);
  asm volatile("s_waitcnt vmcnt(4)" ::: "memory");
  __builtin_amdgcn_s_barrier();

  for (int t = 0; t < 16; ++t) {
    const int rp = t & 1, sp = rp ^ 1, kt = t + 1;
    const bool pf = (t < 15);
    // ---- ph0: MFMA(0,0)
    LDA(0);
    LDB(0);
    if (pf) {
      stage_a(0, sp, kt);
      asm volatile("s_waitcnt vmcnt(4)" ::: "memory");
    } else {
      asm volatile("s_waitcnt vmcnt(0)" ::: "memory");
    }
    __builtin_amdgcn_s_barrier();
    MFMAQ(0, 0);
    __builtin_amdgcn_s_barrier();
    // ---- ph1: MFMA(0,1)
    LDB(1);
    if (pf) {
      stage_b(0, sp, kt);
      asm volatile("s_waitcnt vmcnt(4)" ::: "memory");
    }
    __builtin_amdgcn_s_barrier();
    MFMAQ(0, 1);
    __builtin_amdgcn_s_barrier();
    // ---- ph2: MFMA(1,1)
    LDA(1);
    if (pf) {
      stage_b(1, sp, kt);
      asm volatile("s_waitcnt vmcnt(4)" ::: "memory");
    }
    __builtin_amdgcn_s_barrier();
    MFMAQ(1, 1);
    __builtin_amdgcn_s_barrier();
    // ---- ph3: MFMA(1,0) (pure register phase; vmcnt covers next ph0's reads)
    if (pf) {
      stage_a(1, sp, kt);
      asm volatile("s_waitcnt vmcnt(4)" ::: "memory");
    }
    __builtin_amdgcn_s_barrier();
    MFMAQ(1, 0);
    __builtin_amdgcn_s_barrier();
  }

  // epilogue: per row, (max, within-margin bitmask) over this wave's 64 h.
  // C/D frag layout: col(h) = lane&15, row-in-frag = (lane>>4)*4 + j.
  const int tile = bn * 4 + wn;  // 64-wide h-tile id (h base = bn*256 + wn*64)
#pragma unroll
  for (int m = 0; m < 8; ++m) {
    float v[4];
#pragma unroll
    for (int j = 0; j < 4; ++j)
      v[j] = fmaxf(fmaxf(acc[m][0][j], acc[m][1][j]), fmaxf(acc[m][2][j], acc[m][3][j]));
#pragma unroll
    for (int s = 1; s < 16; s <<= 1) {
#pragma unroll
      for (int j = 0; j < 4; ++j) v[j] = fmaxf(v[j], __shfl_xor(v[j], s));
    }
    unsigned long long mk[4];
#pragma unroll
    for (int j = 0; j < 4; ++j) {
      unsigned long long bmask = 0;
      const float thr = v[j] - MARGIN;
#pragma unroll
      for (int n = 0; n < 4; ++n)
        if (acc[m][n][j] >= thr) bmask |= 1ull << (n * 16 + r15);
      mk[j] = bmask;
    }
#pragma unroll
    for (int s = 1; s < 16; s <<= 1) {
#pragma unroll
      for (int j = 0; j < 4; ++j) mk[j] |= __shfl_xor(mk[j], s);
    }
    if (r15 == 0) {
#pragma unroll
      for (int j = 0; j < 4; ++j) {
        const int row = bm * 256 + wm * 128 + m * 16 + g * 4 + j;
        tmax64[(size_t)row * 64 + tile] = v[j];
        tmask64[(size_t)row * 64 + tile] = mk[j];
      }
    }
  }
}

// ---------------- phase 2: exact f64 rescore of candidate h's (one wave per row) ----------------
__global__ __launch_bounds__(64) void rescore2(const float* __restrict__ x,
                                               const float* __restrict__ w,
                                               const double* __restrict__ w2d,
                                               const float* __restrict__ tmax64,
                                               const unsigned long long* __restrict__ tmask64,
                                               int* __restrict__ winners,
                                               float* __restrict__ winners_f) {
  const int row = blockIdx.x;
  const int l = threadIdx.x;

  f32x4 xr[4];
  const f32x4* xp = reinterpret_cast<const f32x4*>(x + (size_t)row * D_SZ);
#pragma unroll
  for (int j = 0; j < 4; ++j) xr[j] = xp[j * 64 + l];

  const float pmax = tmax64[(size_t)row * 64 + l];
  const unsigned long long pmask = tmask64[(size_t)row * 64 + l];
  float M = pmax;
#pragma unroll
  for (int m = 1; m < 64; m <<= 1) M = fmaxf(M, __shfl_xor(M, m));
  const float thr = M - MARGIN;

  double bestS = -1e300;
  int bestI = 0x7fffffff;

  unsigned long long bits = __ballot(pmax >= thr && pmask != 0ull);
  while (bits) {
    const int src = __ffsll(bits) - 1;
    unsigned long long tmask = __shfl(pmask, src);
    const int tile = src;
    while (tmask) {
      const int b = __ffsll(tmask) - 1;
      const int h = tile * 64 + b;
      const f32x4* wp = reinterpret_cast<const f32x4*>(w + (size_t)h * D_SZ);
      double dot = 0.0;
#pragma unroll
      for (int j = 0; j < 4; ++j) {
        f32x4 wv = wp[j * 64 + l];
        dot += (double)xr[j][0] * wv[0] + (double)xr[j][1] * wv[1] +
               (double)xr[j][2] * wv[2] + (double)xr[j][3] * wv[3];
      }
#pragma unroll
      for (int m = 32; m; m >>= 1) dot += __shfl_xor(dot, m);
      const double sc = 2.0 * dot - w2d[h];  // maximize  <=>  minimize d2
      if (sc > bestS || (sc == bestS && h < bestI)) { bestS = sc; bestI = h; }
      tmask &= tmask - 1;
    }
    bits &= bits - 1;
  }

  if (l == 0) { winners[row] = bestI; winners_f[row] = (float)bestI; }
}

// ---------------- phase 3a: transpose grossberg [O][H] -> GT [H][O] ----------------
__global__ __launch_bounds__(256) void transpose_g(const float* __restrict__ g,
                                                   float* __restrict__ gt) {
  __shared__ float t[32][33];
  const int h0 = blockIdx.x * 32;
  const int o0 = blockIdx.y * 32;
  const int lx = threadIdx.x & 31, ly = threadIdx.x >> 5;
  for (int i = ly; i < 32; i += 8) {
    const int o = o0 + i;
    t[i][lx] = (o < O_SZ) ? g[(size_t)o * H_SZ + (h0 + lx)] : 0.f;
  }
  __syncthreads();
  for (int i = ly; i < 32; i += 8) {
    const int o = o0 + lx;
    if (o < O_SZ) gt[(size_t)(h0 + i) * O_SZ + o] = t[lx][i];
  }
}

// ---------------- phase 3b: row gather + scalar ----------------
__global__ __launch_bounds__(256) void gather_out(const float* __restrict__ gt,
                                                  const int* __restrict__ winners,
                                                  float* __restrict__ out) {
  const int row = blockIdx.x;
  const int wsel = winners[row];
  const f32x4* src = reinterpret_cast<const f32x4*>(gt + (size_t)wsel * O_SZ);
  f32x4* dst = reinterpret_cast<f32x4*>(out + (size_t)row * O_SZ);
  if (threadIdx.x < O_SZ / 4) dst[threadIdx.x] = src[threadIdx.x];
  if (row == 0 && threadIdx.x == 0)
    out[(size_t)B_SZ * O_SZ + B_SZ] = (float)B_SZ;  // scalar output: x.shape[0]
}

// ---------------- launch ----------------
extern "C" void kernel_launch(void* const* d_in, const int* in_sizes, int n_in,
                              void* d_out, int out_size, void* d_ws, size_t ws_size,
                              hipStream_t stream) {
  const float* x  = (const float*)d_in[0];
  const float* kw = (const float*)d_in[1];
  const float* gw = (const float*)d_in[2];
  float* out = (float*)d_out;
  char* ws = (char*)d_ws;

  // ws layout (bytes):
  //   xb      @ 0          : 8192*1024*2 = 16,777,216
  //   wb      @ 16,777,216 : 4096*1024*2 =  8,388,608
  //   tmax64  @ 25,165,824 : 8192*64*4   =  2,097,152
  //   tmask64 @ 27,262,976 : 8192*64*8   =  4,194,304
  //   winners @ 31,457,280 : 8192*4      =     32,768
  //   w2d     @ 31,490,048 : 4096*8      =     32,768
  //   GT aliases xb (16,384,000 <= 16,777,216; xb is dead after phase 1)
  uint16_t*           xb   = (uint16_t*)(ws);
  uint16_t*           wb   = (uint16_t*)(ws + 16777216);
  float*              tmx  = (float*)   (ws + 25165824);
  unsigned long long* tmk  = (unsigned long long*)(ws + 27262976);
  int*                wins = (int*)     (ws + 31457280);
  double*             w2d  = (double*)  (ws + 31490048);
  float*              gt   = (float*)   (ws);  // alias of xb, used after phase 2

  convert_bf16<<<(B_SZ * D_SZ / 4 + 255) / 256, 256, 0, stream>>>(x, (ushort4*)xb, B_SZ * D_SZ / 4);
  convert_bf16<<<(H_SZ * D_SZ / 4 + 255) / 256, 256, 0, stream>>>(kw, (ushort4*)wb, H_SZ * D_SZ / 4);
  w2_kernel<<<H_SZ, 64, 0, stream>>>(kw, w2d);

  static bool attr_set = false;
  if (!attr_set) {
    hipFuncSetAttribute((const void*)kohonen_gemm256,
                        hipFuncAttributeMaxDynamicSharedMemorySize, 131072);
    attr_set = true;
  }
  kohonen_gemm256<<<512, 512, 131072, stream>>>(xb, wb, tmx, tmk);

  rescore2<<<B_SZ, 64, 0, stream>>>(x, kw, w2d, tmx, tmk, wins, out + (size_t)B_SZ * O_SZ);

  dim3 g3(H_SZ / 32, (O_SZ + 31) / 32);
  transpose_g<<<g3, 256, 0, stream>>>(gw, gt);

  gather_out<<<B_SZ, 256, 0, stream>>>(gt, wins, out);
}

// Round 9
// 123.285 us; speedup vs baseline: 1.5681x; 1.0600x over previous
//
#include <hip/hip_runtime.h>
#include <stdint.h>

#define B_SZ 8192
#define D_SZ 1024
#define H_SZ 4096
#define O_SZ 1000

#define MARGIN 0.0625f

typedef float f32x4 __attribute__((ext_vector_type(4)));
typedef __bf16 bf16x8 __attribute__((ext_vector_type(8)));

// ---------------- fp32 -> bf16 (round-to-nearest-even) ----------------
static __device__ __forceinline__ uint16_t f2bf(float f) {
  uint32_t u = __float_as_uint(f);
  uint32_t r = (u + 0x7fffu + ((u >> 16) & 1u)) >> 16;
  return (uint16_t)r;
}

__global__ __launch_bounds__(256) void convert_bf16(const float* __restrict__ src,
                                                    ushort4* __restrict__ dst, int n4) {
  int i = blockIdx.x * blockDim.x + threadIdx.x;
  if (i < n4) {
    f32x4 v = reinterpret_cast<const f32x4*>(src)[i];
    ushort4 o;
    o.x = f2bf(v[0]); o.y = f2bf(v[1]); o.z = f2bf(v[2]); o.w = f2bf(v[3]);
    dst[i] = o;
  }
}

// ---------------- fused: w -> bf16 AND w2 in f64 (single pass over w) ----------------
__global__ __launch_bounds__(64) void convert_w_w2(const float* __restrict__ w,
                                                   uint16_t* __restrict__ wb,
                                                   double* __restrict__ w2d) {
  const int h = blockIdx.x;
  const int l = threadIdx.x;
  const f32x4* wr = reinterpret_cast<const f32x4*>(w + (size_t)h * D_SZ);
  ushort4* wo = reinterpret_cast<ushort4*>(wb + (size_t)h * D_SZ);
  double s = 0.0;
#pragma unroll
  for (int j = 0; j < 4; ++j) {
    f32x4 v = wr[j * 64 + l];
    s += (double)v[0] * v[0] + (double)v[1] * v[1] + (double)v[2] * v[2] + (double)v[3] * v[3];
    ushort4 o;
    o.x = f2bf(v[0]); o.y = f2bf(v[1]); o.z = f2bf(v[2]); o.w = f2bf(v[3]);
    wo[j * 64 + l] = o;
  }
#pragma unroll
  for (int m = 32; m; m >>= 1) s += __shfl_xor(s, m);
  if (l == 0) w2d[h] = s;
}

// ---------------- phase 1: 256x256 8-phase bf16 MFMA GEMM (24-read, R7 schedule) --------
// 8 waves (2M x 4N), per-wave C = 128x64 (8 m-frags x 4 n-frags of 16x16), BK=64.
// Schedule identical to R7 (verified absmax-0). Changed THIS round: the LDS swizzle.
// Derivation (R7 counters): 4 conflict-cyc/read because consecutive lane-octets (g=0,
// r15=0..7) hit only 2 of 8 16B chunk-slots. Fix = Guideline-4's row-stripe XOR:
//   read  byte ^= (slot_row & 7) << 4      (each octet now covers all 8 slots)
//   write source part = lp ^ lr            (same per-row involution; linear glds dest)
__global__ __launch_bounds__(512, 2) void kohonen_gemm256(const uint16_t* __restrict__ xb,
                                                          const uint16_t* __restrict__ wb,
                                                          float* __restrict__ tmax64,
                                                          unsigned long long* __restrict__ tmask64) {
  extern __shared__ char smem[];  // 131072 B: A slots @0, B slots @65536
  const int tid = threadIdx.x;
  const int lane = tid & 63, wid = tid >> 6;
  const int wm = wid >> 2, wn = wid & 3;
  const int r15 = lane & 15, g = lane >> 4;
  const int xorv = (r15 & 7) << 4;          // row-stripe chunk swizzle (read side)
  const int lr = lane >> 3, lp = lane & 7;  // staging: row-within-8, 16B part

  // XCD-bijective swizzle: 512 blocks = 8 XCDs x 64
  const int bid = blockIdx.x;
  const int wg = (bid & 7) * 64 + (bid >> 3);
  const int bm = wg >> 4, bn = wg & 15;

  const uint16_t* xrow = xb + (size_t)(bm * 256) * D_SZ;
  const uint16_t* wrow = wb + (size_t)(bn * 256) * D_SZ;

  f32x4 acc[8][4] = {};
  bf16x8 Af[4][2];      // current qm-half of A: [mi][ks]
  bf16x8 Bf[2][2][2];   // both qn-halves of B: [qn][ni][ks]

  auto stage_a = [&](int a, int sp, int kt) {
#pragma unroll
    for (int j = 0; j < 2; ++j) {
      const int pp = lp ^ lr;  // source chunk for row-stripe involution
      const int sr = wid * 16 + j * 8 + lr;
      const int mr = (sr < 64) ? (a * 64 + sr) : (128 + a * 64 + (sr - 64));
      const uint16_t* src = xrow + (size_t)mr * D_SZ + kt * 64 + pp * 8;
      __builtin_amdgcn_global_load_lds(
          (const __attribute__((address_space(1))) uint32_t*)src,
          (__attribute__((address_space(3))) uint32_t*)(smem + (sp * 2 + a) * 16384 +
                                                        (wid * 16 + j * 8) * 128),
          16, 0, 0);
    }
  };
  auto stage_b = [&](int b, int sp, int kt) {
#pragma unroll
    for (int j = 0; j < 2; ++j) {
      const int pp = lp ^ lr;
      const int sr = wid * 16 + j * 8 + lr;
      const int mr = (sr >> 5) * 64 + b * 32 + (sr & 31);
      const uint16_t* src = wrow + (size_t)mr * D_SZ + kt * 64 + pp * 8;
      __builtin_amdgcn_global_load_lds(
          (const __attribute__((address_space(1))) uint32_t*)src,
          (__attribute__((address_space(3))) uint32_t*)(smem + 65536 + (sp * 2 + b) * 16384 +
                                                        (wid * 16 + j * 8) * 128),
          16, 0, 0);
    }
  };

#define LDA(QM)                                                                  \
  {                                                                              \
    const char* Abq = smem + rp * 32768 + (QM)*16384;                            \
    _Pragma("unroll") for (int mi = 0; mi < 4; ++mi) {                           \
      const int sr = wm * 64 + mi * 16 + r15;                                    \
      _Pragma("unroll") for (int ks = 0; ks < 2; ++ks)                           \
          Af[mi][ks] = *reinterpret_cast<const bf16x8*>(                         \
              Abq + ((sr * 128 + ks * 64 + g * 16) ^ xorv));                     \
    }                                                                            \
  }
#define LDB(QN)                                                                  \
  {                                                                              \
    const char* Bbq = smem + 65536 + rp * 32768 + (QN)*16384;                    \
    _Pragma("unroll") for (int ni = 0; ni < 2; ++ni) {                           \
      const int sr = wn * 32 + ni * 16 + r15;                                    \
      _Pragma("unroll") for (int ks = 0; ks < 2; ++ks)                           \
          Bf[QN][ni][ks] = *reinterpret_cast<const bf16x8*>(                     \
              Bbq + ((sr * 128 + ks * 64 + g * 16) ^ xorv));                     \
    }                                                                            \
  }
#define MFMAQ(QM, QN)                                                            \
  __builtin_amdgcn_s_setprio(1);                                                 \
  _Pragma("unroll") for (int mi = 0; mi < 4; ++mi)                               \
      _Pragma("unroll") for (int ni = 0; ni < 2; ++ni)                           \
          _Pragma("unroll") for (int ks = 0; ks < 2; ++ks)                       \
              acc[(QM)*4 + mi][(QN)*2 + ni] = __builtin_amdgcn_mfma_f32_16x16x32_bf16( \
                  Af[mi][ks], Bf[QN][ni][ks], acc[(QM)*4 + mi][(QN)*2 + ni], 0, 0, 0); \
  __builtin_amdgcn_s_setprio(0);

  // prologue: tile 0 -> parity 0, order A0,B0,B1,A1; then retire A0,B0 before iter0 reads
  stage_a(0, 0, 0);
  stage_b(0, 0, 0);
  stage_b(1, 0, 0);
  stage_a(1, 0, 0);
  asm volatile("s_waitcnt vmcnt(4)" ::: "memory");
  __builtin_amdgcn_s_barrier();

  for (int t = 0; t < 16; ++t) {
    const int rp = t & 1, sp = rp ^ 1, kt = t + 1;
    const bool pf = (t < 15);
    // ---- ph0: MFMA(0,0)
    LDA(0);
    LDB(0);
    if (pf) {
      stage_a(0, sp, kt);
      asm volatile("s_waitcnt vmcnt(4)" ::: "memory");
    } else {
      asm volatile("s_waitcnt vmcnt(0)" ::: "memory");
    }
    __builtin_amdgcn_s_barrier();
    MFMAQ(0, 0);
    __builtin_amdgcn_s_barrier();
    // ---- ph1: MFMA(0,1)
    LDB(1);
    if (pf) {
      stage_b(0, sp, kt);
      asm volatile("s_waitcnt vmcnt(4)" ::: "memory");
    }
    __builtin_amdgcn_s_barrier();
    MFMAQ(0, 1);
    __builtin_amdgcn_s_barrier();
    // ---- ph2: MFMA(1,1)
    LDA(1);
    if (pf) {
      stage_b(1, sp, kt);
      asm volatile("s_waitcnt vmcnt(4)" ::: "memory");
    }
    __builtin_amdgcn_s_barrier();
    MFMAQ(1, 1);
    __builtin_amdgcn_s_barrier();
    // ---- ph3: MFMA(1,0) (pure register phase; vmcnt covers next ph0's reads)
    if (pf) {
      stage_a(1, sp, kt);
      asm volatile("s_waitcnt vmcnt(4)" ::: "memory");
    }
    __builtin_amdgcn_s_barrier();
    MFMAQ(1, 0);
    __builtin_amdgcn_s_barrier();
  }

  // epilogue: per row, (max, within-margin bitmask) over this wave's 64 h.
  // C/D frag layout: col(h) = lane&15, row-in-frag = (lane>>4)*4 + j.
  const int tile = bn * 4 + wn;  // 64-wide h-tile id (h base = bn*256 + wn*64)
#pragma unroll
  for (int m = 0; m < 8; ++m) {
    float v[4];
#pragma unroll
    for (int j = 0; j < 4; ++j)
      v[j] = fmaxf(fmaxf(acc[m][0][j], acc[m][1][j]), fmaxf(acc[m][2][j], acc[m][3][j]));
#pragma unroll
    for (int s = 1; s < 16; s <<= 1) {
#pragma unroll
      for (int j = 0; j < 4; ++j) v[j] = fmaxf(v[j], __shfl_xor(v[j], s));
    }
    unsigned long long mk[4];
#pragma unroll
    for (int j = 0; j < 4; ++j) {
      unsigned long long bmask = 0;
      const float thr = v[j] - MARGIN;
#pragma unroll
      for (int n = 0; n < 4; ++n)
        if (acc[m][n][j] >= thr) bmask |= 1ull << (n * 16 + r15);
      mk[j] = bmask;
    }
#pragma unroll
    for (int s = 1; s < 16; s <<= 1) {
#pragma unroll
      for (int j = 0; j < 4; ++j) mk[j] |= __shfl_xor(mk[j], s);
    }
    if (r15 == 0) {
#pragma unroll
      for (int j = 0; j < 4; ++j) {
        const int row = bm * 256 + wm * 128 + m * 16 + g * 4 + j;
        tmax64[(size_t)row * 64 + tile] = v[j];
        tmask64[(size_t)row * 64 + tile] = mk[j];
      }
    }
  }
}

// ---------------- phase 2: exact f64 rescore of candidate h's (one wave per row) ----------------
__global__ __launch_bounds__(64) void rescore2(const float* __restrict__ x,
                                               const float* __restrict__ w,
                                               const double* __restrict__ w2d,
                                               const float* __restrict__ tmax64,
                                               const unsigned long long* __restrict__ tmask64,
                                               int* __restrict__ winners,
                                               float* __restrict__ winners_f) {
  const int row = blockIdx.x;
  const int l = threadIdx.x;

  f32x4 xr[4];
  const f32x4* xp = reinterpret_cast<const f32x4*>(x + (size_t)row * D_SZ);
#pragma unroll
  for (int j = 0; j < 4; ++j) xr[j] = xp[j * 64 + l];

  const float pmax = tmax64[(size_t)row * 64 + l];
  const unsigned long long pmask = tmask64[(size_t)row * 64 + l];
  float M = pmax;
#pragma unroll
  for (int m = 1; m < 64; m <<= 1) M = fmaxf(M, __shfl_xor(M, m));
  const float thr = M - MARGIN;

  double bestS = -1e300;
  int bestI = 0x7fffffff;

  unsigned long long bits = __ballot(pmax >= thr && pmask != 0ull);
  while (bits) {
    const int src = __ffsll(bits) - 1;
    unsigned long long tmask = __shfl(pmask, src);
    const int tile = src;
    while (tmask) {
      const int b = __ffsll(tmask) - 1;
      const int h = tile * 64 + b;
      const f32x4* wp = reinterpret_cast<const f32x4*>(w + (size_t)h * D_SZ);
      double dot = 0.0;
#pragma unroll
      for (int j = 0; j < 4; ++j) {
        f32x4 wv = wp[j * 64 + l];
        dot += (double)xr[j][0] * wv[0] + (double)xr[j][1] * wv[1] +
               (double)xr[j][2] * wv[2] + (double)xr[j][3] * wv[3];
      }
#pragma unroll
      for (int m = 32; m; m >>= 1) dot += __shfl_xor(dot, m);
      const double sc = 2.0 * dot - w2d[h];  // maximize  <=>  minimize d2
      if (sc > bestS || (sc == bestS && h < bestI)) { bestS = sc; bestI = h; }
      tmask &= tmask - 1;
    }
    bits &= bits - 1;
  }

  if (l == 0) { winners[row] = bestI; winners_f[row] = (float)bestI; }
}

// ---------------- phase 3a: transpose grossberg [O][H] -> GT [H][O] ----------------
__global__ __launch_bounds__(256) void transpose_g(const float* __restrict__ g,
                                                   float* __restrict__ gt) {
  __shared__ float t[32][33];
  const int h0 = blockIdx.x * 32;
  const int o0 = blockIdx.y * 32;
  const int lx = threadIdx.x & 31, ly = threadIdx.x >> 5;
  for (int i = ly; i < 32; i += 8) {
    const int o = o0 + i;
    t[i][lx] = (o < O_SZ) ? g[(size_t)o * H_SZ + (h0 + lx)] : 0.f;
  }
  __syncthreads();
  for (int i = ly; i < 32; i += 8) {
    const int o = o0 + lx;
    if (o < O_SZ) gt[(size_t)(h0 + i) * O_SZ + o] = t[lx][i];
  }
}

// ---------------- phase 3b: row gather + scalar ----------------
__global__ __launch_bounds__(256) void gather_out(const float* __restrict__ gt,
                                                  const int* __restrict__ winners,
                                                  float* __restrict__ out) {
  const int row = blockIdx.x;
  const int wsel = winners[row];
  const f32x4* src = reinterpret_cast<const f32x4*>(gt + (size_t)wsel * O_SZ);
  f32x4* dst = reinterpret_cast<f32x4*>(out + (size_t)row * O_SZ);
  if (threadIdx.x < O_SZ / 4) dst[threadIdx.x] = src[threadIdx.x];
  if (row == 0 && threadIdx.x == 0)
    out[(size_t)B_SZ * O_SZ + B_SZ] = (float)B_SZ;  // scalar output: x.shape[0]
}

// ---------------- launch ----------------
extern "C" void kernel_launch(void* const* d_in, const int* in_sizes, int n_in,
                              void* d_out, int out_size, void* d_ws, size_t ws_size,
                              hipStream_t stream) {
  const float* x  = (const float*)d_in[0];
  const float* kw = (const float*)d_in[1];
  const float* gw = (const float*)d_in[2];
  float* out = (float*)d_out;
  char* ws = (char*)d_ws;

  // ws layout (bytes):
  //   xb      @ 0          : 8192*1024*2 = 16,777,216
  //   wb      @ 16,777,216 : 4096*1024*2 =  8,388,608
  //   tmax64  @ 25,165,824 : 8192*64*4   =  2,097,152
  //   tmask64 @ 27,262,976 : 8192*64*8   =  4,194,304
  //   winners @ 31,457,280 : 8192*4      =     32,768
  //   w2d     @ 31,490,048 : 4096*8      =     32,768
  //   GT aliases xb (16,384,000 <= 16,777,216; xb is dead after phase 1)
  uint16_t*           xb   = (uint16_t*)(ws);
  uint16_t*           wb   = (uint16_t*)(ws + 16777216);
  float*              tmx  = (float*)   (ws + 25165824);
  unsigned long long* tmk  = (unsigned long long*)(ws + 27262976);
  int*                wins = (int*)     (ws + 31457280);
  double*             w2d  = (double*)  (ws + 31490048);
  float*              gt   = (float*)   (ws);  // alias of xb, used after phase 2

  convert_bf16<<<(B_SZ * D_SZ / 4 + 255) / 256, 256, 0, stream>>>(x, (ushort4*)xb, B_SZ * D_SZ / 4);
  convert_w_w2<<<H_SZ, 64, 0, stream>>>(kw, wb, w2d);

  static bool attr_set = false;
  if (!attr_set) {
    hipFuncSetAttribute((const void*)kohonen_gemm256,
                        hipFuncAttributeMaxDynamicSharedMemorySize, 131072);
    attr_set = true;
  }
  kohonen_gemm256<<<512, 512, 131072, stream>>>(xb, wb, tmx, tmk);

  rescore2<<<B_SZ, 64, 0, stream>>>(x, kw, w2d, tmx, tmk, wins, out + (size_t)B_SZ * O_SZ);

  dim3 g3(H_SZ / 32, (O_SZ + 31) / 32);
  transpose_g<<<g3, 256, 0, stream>>>(gw, gt);

  gather_out<<<B_SZ, 256, 0, stream>>>(gt, wins, out);
}

// Round 10
// 118.782 us; speedup vs baseline: 1.6276x; 1.0379x over previous
//
#include <hip/hip_runtime.h>
#include <stdint.h>

#define B_SZ 8192
#define D_SZ 1024
#define H_SZ 4096
#define O_SZ 1000

#define MARGIN 0.0625f

typedef float f32x4 __attribute__((ext_vector_type(4)));
typedef __bf16 bf16x8 __attribute__((ext_vector_type(8)));

// ---------------- fp32 -> bf16 (round-to-nearest-even) ----------------
static __device__ __forceinline__ uint16_t f2bf(float f) {
  uint32_t u = __float_as_uint(f);
  uint32_t r = (u + 0x7fffu + ((u >> 16) & 1u)) >> 16;
  return (uint16_t)r;
}

__global__ __launch_bounds__(256) void convert_bf16(const float* __restrict__ src,
                                                    ushort4* __restrict__ dst, int n4) {
  int i = blockIdx.x * blockDim.x + threadIdx.x;
  if (i < n4) {
    f32x4 v = reinterpret_cast<const f32x4*>(src)[i];
    ushort4 o;
    o.x = f2bf(v[0]); o.y = f2bf(v[1]); o.z = f2bf(v[2]); o.w = f2bf(v[3]);
    dst[i] = o;
  }
}

// ---------------- fused: w -> bf16 AND w2 in f64 (single pass over w) ----------------
__global__ __launch_bounds__(64) void convert_w_w2(const float* __restrict__ w,
                                                   uint16_t* __restrict__ wb,
                                                   double* __restrict__ w2d) {
  const int h = blockIdx.x;
  const int l = threadIdx.x;
  const f32x4* wr = reinterpret_cast<const f32x4*>(w + (size_t)h * D_SZ);
  ushort4* wo = reinterpret_cast<ushort4*>(wb + (size_t)h * D_SZ);
  double s = 0.0;
#pragma unroll
  for (int j = 0; j < 4; ++j) {
    f32x4 v = wr[j * 64 + l];
    s += (double)v[0] * v[0] + (double)v[1] * v[1] + (double)v[2] * v[2] + (double)v[3] * v[3];
    ushort4 o;
    o.x = f2bf(v[0]); o.y = f2bf(v[1]); o.z = f2bf(v[2]); o.w = f2bf(v[3]);
    wo[j * 64 + l] = o;
  }
#pragma unroll
  for (int m = 32; m; m >>= 1) s += __shfl_xor(s, m);
  if (l == 0) w2d[h] = s;
}

// ---------------- phase 1: 256x256 bf16 MFMA GEMM — single-barrier phases ----------------
// R9 schedule minus the post-MFMA barrier (4 barriers/K-tile). Safety walk:
//  * MFMA consumes registers only; after the pre-MFMA barrier a wave's LDS data is consumed.
//  * Phase-ph reads (rp slots): retirement across ALL waves was guaranteed before the
//    barrier each wave passed immediately prior — P1..P4 by bar(t-1,ph3) [t-1 ph2/ph3
//    vmcnt(4) retire P1,P2 / P3,P4], P5,P6 by bar(t,ph0), P7,P8 by bar(t,ph1).
//  * Stage writes (sp slots) conflict with no reads this t; the t-boundary overwrite of
//    old-rp slots issues only after bar(t-1,ph3), and every wave's old-rp ds_reads
//    completed before it arrived there (in-order issue: MFMA(ph2) issued => lgkm drained).
//  * vmcnt is a per-wave FIFO — unaffected by barrier removal.
// LDS swizzle (R9-verified, conflicts==0): read byte ^= (r15&7)<<4; source part = lp^lr.
__global__ __launch_bounds__(512, 2) void kohonen_gemm256(const uint16_t* __restrict__ xb,
                                                          const uint16_t* __restrict__ wb,
                                                          float* __restrict__ tmax64,
                                                          unsigned long long* __restrict__ tmask64) {
  extern __shared__ char smem[];  // 131072 B: A slots @0, B slots @65536
  const int tid = threadIdx.x;
  const int lane = tid & 63, wid = tid >> 6;
  const int wm = wid >> 2, wn = wid & 3;
  const int r15 = lane & 15, g = lane >> 4;
  const int xorv = (r15 & 7) << 4;          // row-stripe chunk swizzle (read side)
  const int lr = lane >> 3, lp = lane & 7;  // staging: row-within-8, 16B part

  // XCD-bijective swizzle: 512 blocks = 8 XCDs x 64
  const int bid = blockIdx.x;
  const int wg = (bid & 7) * 64 + (bid >> 3);
  const int bm = wg >> 4, bn = wg & 15;

  const uint16_t* xrow = xb + (size_t)(bm * 256) * D_SZ;
  const uint16_t* wrow = wb + (size_t)(bn * 256) * D_SZ;

  f32x4 acc[8][4] = {};
  bf16x8 Af[4][2];      // current qm-half of A: [mi][ks]
  bf16x8 Bf[2][2][2];   // both qn-halves of B: [qn][ni][ks]

  auto stage_a = [&](int a, int sp, int kt) {
#pragma unroll
    for (int j = 0; j < 2; ++j) {
      const int pp = lp ^ lr;  // source chunk for row-stripe involution
      const int sr = wid * 16 + j * 8 + lr;
      const int mr = (sr < 64) ? (a * 64 + sr) : (128 + a * 64 + (sr - 64));
      const uint16_t* src = xrow + (size_t)mr * D_SZ + kt * 64 + pp * 8;
      __builtin_amdgcn_global_load_lds(
          (const __attribute__((address_space(1))) uint32_t*)src,
          (__attribute__((address_space(3))) uint32_t*)(smem + (sp * 2 + a) * 16384 +
                                                        (wid * 16 + j * 8) * 128),
          16, 0, 0);
    }
  };
  auto stage_b = [&](int b, int sp, int kt) {
#pragma unroll
    for (int j = 0; j < 2; ++j) {
      const int pp = lp ^ lr;
      const int sr = wid * 16 + j * 8 + lr;
      const int mr = (sr >> 5) * 64 + b * 32 + (sr & 31);
      const uint16_t* src = wrow + (size_t)mr * D_SZ + kt * 64 + pp * 8;
      __builtin_amdgcn_global_load_lds(
          (const __attribute__((address_space(1))) uint32_t*)src,
          (__attribute__((address_space(3))) uint32_t*)(smem + 65536 + (sp * 2 + b) * 16384 +
                                                        (wid * 16 + j * 8) * 128),
          16, 0, 0);
    }
  };

#define LDA(QM)                                                                  \
  {                                                                              \
    const char* Abq = smem + rp * 32768 + (QM)*16384;                            \
    _Pragma("unroll") for (int mi = 0; mi < 4; ++mi) {                           \
      const int sr = wm * 64 + mi * 16 + r15;                                    \
      _Pragma("unroll") for (int ks = 0; ks < 2; ++ks)                           \
          Af[mi][ks] = *reinterpret_cast<const bf16x8*>(                         \
              Abq + ((sr * 128 + ks * 64 + g * 16) ^ xorv));                     \
    }                                                                            \
  }
#define LDB(QN)                                                                  \
  {                                                                              \
    const char* Bbq = smem + 65536 + rp * 32768 + (QN)*16384;                    \
    _Pragma("unroll") for (int ni = 0; ni < 2; ++ni) {                           \
      const int sr = wn * 32 + ni * 16 + r15;                                    \
      _Pragma("unroll") for (int ks = 0; ks < 2; ++ks)                           \
          Bf[QN][ni][ks] = *reinterpret_cast<const bf16x8*>(                     \
              Bbq + ((sr * 128 + ks * 64 + g * 16) ^ xorv));                     \
    }                                                                            \
  }
#define MFMAQ(QM, QN)                                                            \
  __builtin_amdgcn_s_setprio(1);                                                 \
  _Pragma("unroll") for (int mi = 0; mi < 4; ++mi)                               \
      _Pragma("unroll") for (int ni = 0; ni < 2; ++ni)                           \
          _Pragma("unroll") for (int ks = 0; ks < 2; ++ks)                       \
              acc[(QM)*4 + mi][(QN)*2 + ni] = __builtin_amdgcn_mfma_f32_16x16x32_bf16( \
                  Af[mi][ks], Bf[QN][ni][ks], acc[(QM)*4 + mi][(QN)*2 + ni], 0, 0, 0); \
  __builtin_amdgcn_s_setprio(0);

  // prologue: tile 0 -> parity 0, order A0,B0,B1,A1; retire A0,B0 before iter0 reads
  stage_a(0, 0, 0);
  stage_b(0, 0, 0);
  stage_b(1, 0, 0);
  stage_a(1, 0, 0);
  asm volatile("s_waitcnt vmcnt(4)" ::: "memory");
  __builtin_amdgcn_s_barrier();

  for (int t = 0; t < 16; ++t) {
    const int rp = t & 1, sp = rp ^ 1, kt = t + 1;
    const bool pf = (t < 15);
    // ---- ph0: MFMA(0,0)
    LDA(0);
    LDB(0);
    if (pf) {
      stage_a(0, sp, kt);
      asm volatile("s_waitcnt vmcnt(4)" ::: "memory");
    } else {
      asm volatile("s_waitcnt vmcnt(0)" ::: "memory");
    }
    __builtin_amdgcn_s_barrier();
    MFMAQ(0, 0);
    // ---- ph1: MFMA(0,1)
    LDB(1);
    if (pf) {
      stage_b(0, sp, kt);
      asm volatile("s_waitcnt vmcnt(4)" ::: "memory");
    }
    __builtin_amdgcn_s_barrier();
    MFMAQ(0, 1);
    // ---- ph2: MFMA(1,1)
    LDA(1);
    if (pf) {
      stage_b(1, sp, kt);
      asm volatile("s_waitcnt vmcnt(4)" ::: "memory");
    }
    __builtin_amdgcn_s_barrier();
    MFMAQ(1, 1);
    // ---- ph3: MFMA(1,0) (pure register phase; vmcnt covers next ph0's reads)
    if (pf) {
      stage_a(1, sp, kt);
      asm volatile("s_waitcnt vmcnt(4)" ::: "memory");
    }
    __builtin_amdgcn_s_barrier();
    MFMAQ(1, 0);
  }

  // epilogue: per row, (max, within-margin bitmask) over this wave's 64 h.
  // C/D frag layout: col(h) = lane&15, row-in-frag = (lane>>4)*4 + j.
  const int tile = bn * 4 + wn;  // 64-wide h-tile id (h base = bn*256 + wn*64)
#pragma unroll
  for (int m = 0; m < 8; ++m) {
    float v[4];
#pragma unroll
    for (int j = 0; j < 4; ++j)
      v[j] = fmaxf(fmaxf(acc[m][0][j], acc[m][1][j]), fmaxf(acc[m][2][j], acc[m][3][j]));
#pragma unroll
    for (int s = 1; s < 16; s <<= 1) {
#pragma unroll
      for (int j = 0; j < 4; ++j) v[j] = fmaxf(v[j], __shfl_xor(v[j], s));
    }
    unsigned long long mk[4];
#pragma unroll
    for (int j = 0; j < 4; ++j) {
      unsigned long long bmask = 0;
      const float thr = v[j] - MARGIN;
#pragma unroll
      for (int n = 0; n < 4; ++n)
        if (acc[m][n][j] >= thr) bmask |= 1ull << (n * 16 + r15);
      mk[j] = bmask;
    }
#pragma unroll
    for (int s = 1; s < 16; s <<= 1) {
#pragma unroll
      for (int j = 0; j < 4; ++j) mk[j] |= __shfl_xor(mk[j], s);
    }
    if (r15 == 0) {
#pragma unroll
      for (int j = 0; j < 4; ++j) {
        const int row = bm * 256 + wm * 128 + m * 16 + g * 4 + j;
        tmax64[(size_t)row * 64 + tile] = v[j];
        tmask64[(size_t)row * 64 + tile] = mk[j];
      }
    }
  }
}

// ---------------- phase 2: exact f64 rescore + fused gather (one wave per row) ----------
// All 64 lanes hold identical bestS/bestI after the full butterfly reduce, so the
// grossberg row-gather fuses here (saves the winners round-trip + one kernel).
__global__ __launch_bounds__(64) void rescore_gather(const float* __restrict__ x,
                                                     const float* __restrict__ w,
                                                     const double* __restrict__ w2d,
                                                     const float* __restrict__ tmax64,
                                                     const unsigned long long* __restrict__ tmask64,
                                                     const float* __restrict__ gt,
                                                     float* __restrict__ out,
                                                     float* __restrict__ winners_f) {
  const int row = blockIdx.x;
  const int l = threadIdx.x;

  f32x4 xr[4];
  const f32x4* xp = reinterpret_cast<const f32x4*>(x + (size_t)row * D_SZ);
#pragma unroll
  for (int j = 0; j < 4; ++j) xr[j] = xp[j * 64 + l];

  const float pmax = tmax64[(size_t)row * 64 + l];
  const unsigned long long pmask = tmask64[(size_t)row * 64 + l];
  float M = pmax;
#pragma unroll
  for (int m = 1; m < 64; m <<= 1) M = fmaxf(M, __shfl_xor(M, m));
  const float thr = M - MARGIN;

  double bestS = -1e300;
  int bestI = 0x7fffffff;

  unsigned long long bits = __ballot(pmax >= thr && pmask != 0ull);
  while (bits) {
    const int src = __ffsll(bits) - 1;
    unsigned long long tmask = __shfl(pmask, src);
    const int tile = src;
    while (tmask) {
      const int b = __ffsll(tmask) - 1;
      const int h = tile * 64 + b;
      const f32x4* wp = reinterpret_cast<const f32x4*>(w + (size_t)h * D_SZ);
      double dot = 0.0;
#pragma unroll
      for (int j = 0; j < 4; ++j) {
        f32x4 wv = wp[j * 64 + l];
        dot += (double)xr[j][0] * wv[0] + (double)xr[j][1] * wv[1] +
               (double)xr[j][2] * wv[2] + (double)xr[j][3] * wv[3];
      }
#pragma unroll
      for (int m = 32; m; m >>= 1) dot += __shfl_xor(dot, m);
      const double sc = 2.0 * dot - w2d[h];  // maximize  <=>  minimize d2
      if (sc > bestS || (sc == bestS && h < bestI)) { bestS = sc; bestI = h; }
      tmask &= tmask - 1;
    }
    bits &= bits - 1;
  }

  if (l == 0) winners_f[row] = (float)bestI;
  // fused gather: out[row,:] = gt[bestI,:]  (250 f32x4, 64 lanes, 4 strided iters)
  const f32x4* gsrc = reinterpret_cast<const f32x4*>(gt + (size_t)bestI * O_SZ);
  f32x4* gdst = reinterpret_cast<f32x4*>(out + (size_t)row * O_SZ);
  for (int i = l; i < O_SZ / 4; i += 64) gdst[i] = gsrc[i];
  if (row == 0 && l == 0)
    out[(size_t)B_SZ * O_SZ + B_SZ] = (float)B_SZ;  // scalar output: x.shape[0]
}

// ---------------- phase 3a: transpose grossberg [O][H] -> GT [H][O] ----------------
__global__ __launch_bounds__(256) void transpose_g(const float* __restrict__ g,
                                                   float* __restrict__ gt) {
  __shared__ float t[32][33];
  const int h0 = blockIdx.x * 32;
  const int o0 = blockIdx.y * 32;
  const int lx = threadIdx.x & 31, ly = threadIdx.x >> 5;
  for (int i = ly; i < 32; i += 8) {
    const int o = o0 + i;
    t[i][lx] = (o < O_SZ) ? g[(size_t)o * H_SZ + (h0 + lx)] : 0.f;
  }
  __syncthreads();
  for (int i = ly; i < 32; i += 8) {
    const int o = o0 + lx;
    if (o < O_SZ) gt[(size_t)(h0 + i) * O_SZ + o] = t[lx][i];
  }
}

// ---------------- launch ----------------
extern "C" void kernel_launch(void* const* d_in, const int* in_sizes, int n_in,
                              void* d_out, int out_size, void* d_ws, size_t ws_size,
                              hipStream_t stream) {
  const float* x  = (const float*)d_in[0];
  const float* kw = (const float*)d_in[1];
  const float* gw = (const float*)d_in[2];
  float* out = (float*)d_out;
  char* ws = (char*)d_ws;

  // ws layout (bytes):
  //   xb      @ 0          : 8192*1024*2 = 16,777,216
  //   wb      @ 16,777,216 : 4096*1024*2 =  8,388,608
  //   tmax64  @ 25,165,824 : 8192*64*4   =  2,097,152
  //   tmask64 @ 27,262,976 : 8192*64*8   =  4,194,304
  //   w2d     @ 31,457,280 : 4096*8      =     32,768
  //   GT aliases xb (16,384,000 <= 16,777,216; xb is dead after the GEMM)
  uint16_t*           xb   = (uint16_t*)(ws);
  uint16_t*           wb   = (uint16_t*)(ws + 16777216);
  float*              tmx  = (float*)   (ws + 25165824);
  unsigned long long* tmk  = (unsigned long long*)(ws + 27262976);
  double*             w2d  = (double*)  (ws + 31457280);
  float*              gt   = (float*)   (ws);  // alias of xb, used after the GEMM

  convert_bf16<<<(B_SZ * D_SZ / 4 + 255) / 256, 256, 0, stream>>>(x, (ushort4*)xb, B_SZ * D_SZ / 4);
  convert_w_w2<<<H_SZ, 64, 0, stream>>>(kw, wb, w2d);

  static bool attr_set = false;
  if (!attr_set) {
    hipFuncSetAttribute((const void*)kohonen_gemm256,
                        hipFuncAttributeMaxDynamicSharedMemorySize, 131072);
    attr_set = true;
  }
  kohonen_gemm256<<<512, 512, 131072, stream>>>(xb, wb, tmx, tmk);

  dim3 g3(H_SZ / 32, (O_SZ + 31) / 32);
  transpose_g<<<g3, 256, 0, stream>>>(gw, gt);

  rescore_gather<<<B_SZ, 64, 0, stream>>>(x, kw, w2d, tmx, tmk, gt, out,
                                          out + (size_t)B_SZ * O_SZ);
}